// Round 1
// baseline (162.207 us; speedup 1.0000x reference)
//
#include <hip/hip_runtime.h>

#define D 128
#define EPS 1e-12f

// Kernel 1: one wave (64 lanes) per row; lane i handles 2 consecutive floats.
// inv[row] = 1 / max(sum|z[row,:]|, eps)
__global__ void inv_l1_norm_kernel(const float* __restrict__ z,
                                   float* __restrict__ inv, int N) {
    int wave_in_block = threadIdx.x >> 6;
    int lane = threadIdx.x & 63;
    int row = blockIdx.x * (blockDim.x >> 6) + wave_in_block;
    if (row >= N) return;
    const float2* zp = (const float2*)(z + (size_t)row * D);
    float2 v = zp[lane];
    float s = fabsf(v.x) + fabsf(v.y);
    #pragma unroll
    for (int m = 32; m >= 1; m >>= 1)
        s += __shfl_xor(s, m, 64);
    if (lane == 0) inv[row] = 1.0f / fmaxf(s, EPS);
}

// Kernel 2: 16 lanes per edge (4 edges per wave). Each lane handles 8 floats
// (2x float4) of the 128-wide row. Row reads are contiguous 512B segments.
__global__ void transe_score_kernel(const float* __restrict__ z,
                                    const int* __restrict__ eidx,   // [2, E]: heads then tails
                                    const int* __restrict__ etype,  // [E]
                                    const float* __restrict__ rel,  // [R, D]
                                    const float* __restrict__ inv,  // [N]
                                    float* __restrict__ out, int E) {
    int gtid = blockIdx.x * blockDim.x + threadIdx.x;
    int e = gtid >> 4;
    int lane16 = threadIdx.x & 15;
    if (e >= E) return;

    int h = eidx[e];
    int t = eidx[E + e];
    int r = etype[e];
    float ih = inv[h];
    float it = inv[t];

    const float4* hp = (const float4*)(z + (size_t)h * D) + lane16 * 2;
    const float4* tp = (const float4*)(z + (size_t)t * D) + lane16 * 2;
    const float4* rp = (const float4*)(rel + (size_t)r * D) + lane16 * 2;

    float s = 0.0f;
    #pragma unroll
    for (int k = 0; k < 2; ++k) {
        float4 hv = hp[k];
        float4 tv = tp[k];
        float4 rv = rp[k];
        s += fabsf(fmaf(hv.x, ih, rv.x) - tv.x * it);
        s += fabsf(fmaf(hv.y, ih, rv.y) - tv.y * it);
        s += fabsf(fmaf(hv.z, ih, rv.z) - tv.z * it);
        s += fabsf(fmaf(hv.w, ih, rv.w) - tv.w * it);
    }
    // reduce across the 16-lane group (xor masks 1,2,4,8 stay within group)
    s += __shfl_xor(s, 1, 64);
    s += __shfl_xor(s, 2, 64);
    s += __shfl_xor(s, 4, 64);
    s += __shfl_xor(s, 8, 64);
    if (lane16 == 0) out[e] = -s;
}

extern "C" void kernel_launch(void* const* d_in, const int* in_sizes, int n_in,
                              void* d_out, int out_size, void* d_ws, size_t ws_size,
                              hipStream_t stream) {
    const float* z    = (const float*)d_in[0];
    const int*   eidx = (const int*)d_in[1];
    const int*   etyp = (const int*)d_in[2];
    const float* rel  = (const float*)d_in[3];
    float* out = (float*)d_out;

    int N = in_sizes[0] / D;
    int E = in_sizes[2];

    float* inv = (float*)d_ws;  // N floats

    // Kernel 1: 4 waves per 256-thread block -> 4 rows per block
    int blocks1 = (N + 3) / 4;
    inv_l1_norm_kernel<<<blocks1, 256, 0, stream>>>(z, inv, N);

    // Kernel 2: 16 edges per 256-thread block
    int blocks2 = (E + 15) / 16;
    transe_score_kernel<<<blocks2, 256, 0, stream>>>(z, eidx, etyp, rel, inv, out, E);
}

// Round 2
// 131.495 us; speedup vs baseline: 1.2336x; 1.2336x over previous
//
#include <hip/hip_runtime.h>
#include <hip/hip_fp16.h>

#define D 128
#define EPS 1e-12f

// ---------- fp16-table path ----------

// One wave per row: compute L1 norm via butterfly shuffle, store z/||z||_1 as fp16.
// Lane i handles elements 2i, 2i+1 -> wave writes a contiguous 256B fp16 row.
__global__ void normalize_to_half_kernel(const float* __restrict__ z,
                                         __half* __restrict__ zn, int N) {
    int wave_in_block = threadIdx.x >> 6;
    int lane = threadIdx.x & 63;
    int row = blockIdx.x * (blockDim.x >> 6) + wave_in_block;
    if (row >= N) return;
    const float2* zp = (const float2*)(z + (size_t)row * D);
    float2 v = zp[lane];
    float s = fabsf(v.x) + fabsf(v.y);
    #pragma unroll
    for (int m = 32; m >= 1; m >>= 1)
        s += __shfl_xor(s, m, 64);          // butterfly: all lanes end with the sum
    float inv = 1.0f / fmaxf(s, EPS);
    __half2* znp = (__half2*)(zn + (size_t)row * D);
    znp[lane] = __floats2half2_rn(v.x * inv, v.y * inv);
}

// 16 lanes per edge (4 edges/wave). Each lane: one 16B load per fp16 row
// (8 halves), two float4 loads for the fp32 rel row. fp32 accumulate.
__global__ void transe_score_half_kernel(const __half* __restrict__ zn,
                                         const int* __restrict__ eidx,   // [2,E]
                                         const int* __restrict__ etype,  // [E]
                                         const float* __restrict__ rel,  // [R,D] fp32
                                         float* __restrict__ out, int E) {
    int gtid = blockIdx.x * blockDim.x + threadIdx.x;
    int e = gtid >> 4;
    int lane16 = threadIdx.x & 15;
    if (e >= E) return;

    int h = eidx[e];
    int t = eidx[E + e];
    int r = etype[e];

    float4 hraw = *(const float4*)(zn + (size_t)h * D + lane16 * 8);
    float4 traw = *(const float4*)(zn + (size_t)t * D + lane16 * 8);
    const float4* rp = (const float4*)(rel + (size_t)r * D) + lane16 * 2;
    float4 r0 = rp[0];
    float4 r1 = rp[1];

    const __half2* hh = (const __half2*)&hraw;
    const __half2* th = (const __half2*)&traw;
    float rf[8] = {r0.x, r0.y, r0.z, r0.w, r1.x, r1.y, r1.z, r1.w};

    float s = 0.0f;
    #pragma unroll
    for (int k = 0; k < 4; ++k) {
        float2 hf = __half22float2(hh[k]);
        float2 tf = __half22float2(th[k]);
        s += fabsf(hf.x + rf[2 * k]     - tf.x);
        s += fabsf(hf.y + rf[2 * k + 1] - tf.y);
    }
    s += __shfl_xor(s, 1, 64);
    s += __shfl_xor(s, 2, 64);
    s += __shfl_xor(s, 4, 64);
    s += __shfl_xor(s, 8, 64);
    if (lane16 == 0) out[e] = -s;
}

// ---------- fallback path (round-1, proven) ----------

__global__ void inv_l1_norm_kernel(const float* __restrict__ z,
                                   float* __restrict__ inv, int N) {
    int wave_in_block = threadIdx.x >> 6;
    int lane = threadIdx.x & 63;
    int row = blockIdx.x * (blockDim.x >> 6) + wave_in_block;
    if (row >= N) return;
    const float2* zp = (const float2*)(z + (size_t)row * D);
    float2 v = zp[lane];
    float s = fabsf(v.x) + fabsf(v.y);
    #pragma unroll
    for (int m = 32; m >= 1; m >>= 1)
        s += __shfl_xor(s, m, 64);
    if (lane == 0) inv[row] = 1.0f / fmaxf(s, EPS);
}

__global__ void transe_score_kernel(const float* __restrict__ z,
                                    const int* __restrict__ eidx,
                                    const int* __restrict__ etype,
                                    const float* __restrict__ rel,
                                    const float* __restrict__ inv,
                                    float* __restrict__ out, int E) {
    int gtid = blockIdx.x * blockDim.x + threadIdx.x;
    int e = gtid >> 4;
    int lane16 = threadIdx.x & 15;
    if (e >= E) return;

    int h = eidx[e];
    int t = eidx[E + e];
    int r = etype[e];
    float ih = inv[h];
    float it = inv[t];

    const float4* hp = (const float4*)(z + (size_t)h * D) + lane16 * 2;
    const float4* tp = (const float4*)(z + (size_t)t * D) + lane16 * 2;
    const float4* rp = (const float4*)(rel + (size_t)r * D) + lane16 * 2;

    float s = 0.0f;
    #pragma unroll
    for (int k = 0; k < 2; ++k) {
        float4 hv = hp[k];
        float4 tv = tp[k];
        float4 rv = rp[k];
        s += fabsf(fmaf(hv.x, ih, rv.x) - tv.x * it);
        s += fabsf(fmaf(hv.y, ih, rv.y) - tv.y * it);
        s += fabsf(fmaf(hv.z, ih, rv.z) - tv.z * it);
        s += fabsf(fmaf(hv.w, ih, rv.w) - tv.w * it);
    }
    s += __shfl_xor(s, 1, 64);
    s += __shfl_xor(s, 2, 64);
    s += __shfl_xor(s, 4, 64);
    s += __shfl_xor(s, 8, 64);
    if (lane16 == 0) out[e] = -s;
}

extern "C" void kernel_launch(void* const* d_in, const int* in_sizes, int n_in,
                              void* d_out, int out_size, void* d_ws, size_t ws_size,
                              hipStream_t stream) {
    const float* z    = (const float*)d_in[0];
    const int*   eidx = (const int*)d_in[1];
    const int*   etyp = (const int*)d_in[2];
    const float* rel  = (const float*)d_in[3];
    float* out = (float*)d_out;

    int N = in_sizes[0] / D;
    int E = in_sizes[2];

    size_t need = (size_t)N * D * sizeof(__half);   // 25.6 MB fp16 table
    if (ws_size >= need) {
        __half* zn = (__half*)d_ws;
        int blocks1 = (N + 3) / 4;                  // 4 waves/block, 1 row/wave
        normalize_to_half_kernel<<<blocks1, 256, 0, stream>>>(z, zn, N);
        int blocks2 = (E + 15) / 16;                // 16 edges per 256-thread block
        transe_score_half_kernel<<<blocks2, 256, 0, stream>>>(zn, eidx, etyp, rel, out, E);
    } else {
        float* inv = (float*)d_ws;                  // N floats
        int blocks1 = (N + 3) / 4;
        inv_l1_norm_kernel<<<blocks1, 256, 0, stream>>>(z, inv, N);
        int blocks2 = (E + 15) / 16;
        transe_score_kernel<<<blocks2, 256, 0, stream>>>(z, eidx, etyp, rel, inv, out, E);
    }
}

// Round 3
// 118.632 us; speedup vs baseline: 1.3673x; 1.1084x over previous
//
#include <hip/hip_runtime.h>
#include <hip/hip_fp16.h>

#define D 128
#define EPS 1e-12f
#define FP8_SCALE 64.0f
#define FP8_INV_SCALE 0.015625f

typedef float v2f __attribute__((ext_vector_type(2)));

// ---------- fp8-e4m3 table path ----------

// One wave per row: butterfly L1-norm, store (z/||z||_1)*64 as fp8 e4m3.
// Lane i packs elements 2i, 2i+1 -> ushort; wave writes a contiguous 128B row.
__global__ void normalize_to_fp8_kernel(const float* __restrict__ z,
                                        unsigned char* __restrict__ zn, int N) {
    int wave_in_block = threadIdx.x >> 6;
    int lane = threadIdx.x & 63;
    int row = blockIdx.x * (blockDim.x >> 6) + wave_in_block;
    if (row >= N) return;
    const float2* zp = (const float2*)(z + (size_t)row * D);
    float2 v = zp[lane];
    float s = fabsf(v.x) + fabsf(v.y);
    #pragma unroll
    for (int m = 32; m >= 1; m >>= 1)
        s += __shfl_xor(s, m, 64);              // all lanes end with the sum
    float f = FP8_SCALE / fmaxf(s, EPS);
    int p = __builtin_amdgcn_cvt_pk_fp8_f32(v.x * f, v.y * f, 0, false);
    unsigned short* rowp = (unsigned short*)(zn + (size_t)row * D);
    rowp[lane] = (unsigned short)(p & 0xffff);
}

// 8 lanes per edge (8 edges/wave). Each lane: one uint4 (16 fp8) per z row,
// 4x float4 of the fp32 rel row. fp32 accumulate, 3-step shuffle reduce.
__global__ void transe_score_fp8_kernel(const unsigned char* __restrict__ zn,
                                        const int* __restrict__ eidx,   // [2,E]
                                        const int* __restrict__ etype,  // [E]
                                        const float* __restrict__ rel,  // [R,D] fp32
                                        float* __restrict__ out, int E) {
    int gtid = blockIdx.x * blockDim.x + threadIdx.x;
    int e = gtid >> 3;
    int lane8 = threadIdx.x & 7;
    if (e >= E) return;

    int h = eidx[e];
    int t = eidx[E + e];
    int r = etype[e];

    uint4 hv = ((const uint4*)(zn + (size_t)h * D))[lane8];
    uint4 tv = ((const uint4*)(zn + (size_t)t * D))[lane8];
    const float4* rp = (const float4*)(rel + (size_t)r * D) + lane8 * 4;
    float4 r0 = rp[0], r1 = rp[1], r2 = rp[2], r3 = rp[3];
    float rf[16] = {r0.x, r0.y, r0.z, r0.w, r1.x, r1.y, r1.z, r1.w,
                    r2.x, r2.y, r2.z, r2.w, r3.x, r3.y, r3.z, r3.w};

    unsigned int hw[4] = {hv.x, hv.y, hv.z, hv.w};
    unsigned int tw[4] = {tv.x, tv.y, tv.z, tv.w};

    float s = 0.0f;
    #pragma unroll
    for (int k = 0; k < 4; ++k) {
        v2f h0 = __builtin_amdgcn_cvt_pk_f32_fp8(hw[k], false);
        v2f h1 = __builtin_amdgcn_cvt_pk_f32_fp8(hw[k], true);
        v2f t0 = __builtin_amdgcn_cvt_pk_f32_fp8(tw[k], false);
        v2f t1 = __builtin_amdgcn_cvt_pk_f32_fp8(tw[k], true);
        s += fabsf(fmaf(h0.x - t0.x, FP8_INV_SCALE, rf[4 * k    ]));
        s += fabsf(fmaf(h0.y - t0.y, FP8_INV_SCALE, rf[4 * k + 1]));
        s += fabsf(fmaf(h1.x - t1.x, FP8_INV_SCALE, rf[4 * k + 2]));
        s += fabsf(fmaf(h1.y - t1.y, FP8_INV_SCALE, rf[4 * k + 3]));
    }
    s += __shfl_xor(s, 1, 64);
    s += __shfl_xor(s, 2, 64);
    s += __shfl_xor(s, 4, 64);
    if (lane8 == 0) out[e] = -s;
}

// ---------- fp16 fallback path (round-2, proven) ----------

__global__ void normalize_to_half_kernel(const float* __restrict__ z,
                                         __half* __restrict__ zn, int N) {
    int wave_in_block = threadIdx.x >> 6;
    int lane = threadIdx.x & 63;
    int row = blockIdx.x * (blockDim.x >> 6) + wave_in_block;
    if (row >= N) return;
    const float2* zp = (const float2*)(z + (size_t)row * D);
    float2 v = zp[lane];
    float s = fabsf(v.x) + fabsf(v.y);
    #pragma unroll
    for (int m = 32; m >= 1; m >>= 1)
        s += __shfl_xor(s, m, 64);
    float inv = 1.0f / fmaxf(s, EPS);
    __half2* znp = (__half2*)(zn + (size_t)row * D);
    znp[lane] = __floats2half2_rn(v.x * inv, v.y * inv);
}

__global__ void transe_score_half_kernel(const __half* __restrict__ zn,
                                         const int* __restrict__ eidx,
                                         const int* __restrict__ etype,
                                         const float* __restrict__ rel,
                                         float* __restrict__ out, int E) {
    int gtid = blockIdx.x * blockDim.x + threadIdx.x;
    int e = gtid >> 4;
    int lane16 = threadIdx.x & 15;
    if (e >= E) return;

    int h = eidx[e];
    int t = eidx[E + e];
    int r = etype[e];

    float4 hraw = *(const float4*)(zn + (size_t)h * D + lane16 * 8);
    float4 traw = *(const float4*)(zn + (size_t)t * D + lane16 * 8);
    const float4* rp = (const float4*)(rel + (size_t)r * D) + lane16 * 2;
    float4 r0 = rp[0];
    float4 r1 = rp[1];

    const __half2* hh = (const __half2*)&hraw;
    const __half2* th = (const __half2*)&traw;
    float rf[8] = {r0.x, r0.y, r0.z, r0.w, r1.x, r1.y, r1.z, r1.w};

    float s = 0.0f;
    #pragma unroll
    for (int k = 0; k < 4; ++k) {
        float2 hf = __half22float2(hh[k]);
        float2 tf = __half22float2(th[k]);
        s += fabsf(hf.x + rf[2 * k]     - tf.x);
        s += fabsf(hf.y + rf[2 * k + 1] - tf.y);
    }
    s += __shfl_xor(s, 1, 64);
    s += __shfl_xor(s, 2, 64);
    s += __shfl_xor(s, 4, 64);
    s += __shfl_xor(s, 8, 64);
    if (lane16 == 0) out[e] = -s;
}

extern "C" void kernel_launch(void* const* d_in, const int* in_sizes, int n_in,
                              void* d_out, int out_size, void* d_ws, size_t ws_size,
                              hipStream_t stream) {
    const float* z    = (const float*)d_in[0];
    const int*   eidx = (const int*)d_in[1];
    const int*   etyp = (const int*)d_in[2];
    const float* rel  = (const float*)d_in[3];
    float* out = (float*)d_out;

    int N = in_sizes[0] / D;
    int E = in_sizes[2];

    size_t need_fp8 = (size_t)N * D;                   // 12.8 MB fp8 table
    if (ws_size >= need_fp8) {
        unsigned char* zn = (unsigned char*)d_ws;
        int blocks1 = (N + 3) / 4;                     // 4 waves/block, 1 row/wave
        normalize_to_fp8_kernel<<<blocks1, 256, 0, stream>>>(z, zn, N);
        int blocks2 = (E + 31) / 32;                   // 32 edges per 256-thread block
        transe_score_fp8_kernel<<<blocks2, 256, 0, stream>>>(zn, eidx, etyp, rel, out, E);
    } else {
        __half* zn = (__half*)d_ws;
        int blocks1 = (N + 3) / 4;
        normalize_to_half_kernel<<<blocks1, 256, 0, stream>>>(z, zn, N);
        int blocks2 = (E + 15) / 16;
        transe_score_half_kernel<<<blocks2, 256, 0, stream>>>(zn, eidx, etyp, rel, out, E);
    }
}